// Round 1
// baseline (389.502 us; speedup 1.0000x reference)
//
#include <hip/hip_runtime.h>
#include <math.h>

#define B 8
#define L 200
#define H 128
#define NH 4
#define DH 32
#define NEGV (-4294967295.0f)   /* -2^32 + 1 */

// ---------------------------------------------------------------------------
// Kernel 1: fused projections.
//   Qo  = queries @ Qw.T + Qb
//   Kpo = keys    @ Kw.T + Kb + abs_pos_K
//   Vpo = keys    @ Vw.T + Vb + abs_pos_V
// One block per 8 rows (1600 rows total -> 200 blocks), 128 threads = one
// output channel each. Weights (3 x 64KB) stay hot in L2 across blocks.
// ---------------------------------------------------------------------------
__global__ __launch_bounds__(128) void proj_kernel(
    const float* __restrict__ queries, const float* __restrict__ keys,
    const float* __restrict__ apK, const float* __restrict__ apV,
    const float* __restrict__ Qw, const float* __restrict__ Qb,
    const float* __restrict__ Kw, const float* __restrict__ Kb,
    const float* __restrict__ Vw, const float* __restrict__ Vb,
    float* __restrict__ Qo, float* __restrict__ Kpo, float* __restrict__ Vpo)
{
    const int j    = threadIdx.x;        // output channel 0..127
    const int row0 = blockIdx.x * 8;     // first of 8 rows

    __shared__ float4 qrow[8 * 32];
    __shared__ float4 krow[8 * 32];

    const float4* q4 = (const float4*)queries + row0 * 32;
    const float4* k4 = (const float4*)keys    + row0 * 32;
    for (int idx = j; idx < 256; idx += 128) { qrow[idx] = q4[idx]; krow[idx] = k4[idx]; }
    __syncthreads();

    float accQ[8], accK[8], accV[8];
    const float qb = Qb[j], kb = Kb[j], vb = Vb[j];
    #pragma unroll
    for (int r = 0; r < 8; ++r) { accQ[r] = qb; accK[r] = kb; accV[r] = vb; }

    const float4* Qw4 = (const float4*)Qw + j * 32;
    const float4* Kw4 = (const float4*)Kw + j * 32;
    const float4* Vw4 = (const float4*)Vw + j * 32;

    for (int k = 0; k < 32; ++k) {
        const float4 wq = Qw4[k];
        const float4 wk = Kw4[k];
        const float4 wv = Vw4[k];
        #pragma unroll
        for (int r = 0; r < 8; ++r) {
            const float4 x = qrow[r * 32 + k];
            accQ[r] = fmaf(wq.x, x.x, fmaf(wq.y, x.y, fmaf(wq.z, x.z, fmaf(wq.w, x.w, accQ[r]))));
            const float4 y = krow[r * 32 + k];
            accK[r] = fmaf(wk.x, y.x, fmaf(wk.y, y.y, fmaf(wk.z, y.z, fmaf(wk.w, y.w, accK[r]))));
            accV[r] = fmaf(wv.x, y.x, fmaf(wv.y, y.y, fmaf(wv.z, y.z, fmaf(wv.w, y.w, accV[r]))));
        }
    }

    #pragma unroll
    for (int r = 0; r < 8; ++r) {
        const int i = row0 + r;
        Qo [i * H + j] = accQ[r];
        Kpo[i * H + j] = accK[r] + apK[i * H + j];
        Vpo[i * H + j] = accV[r] + apV[i * H + j];
    }
}

// ---------------------------------------------------------------------------
// Kernel 2: attention. One block per (b,l) query row; 256 threads.
//   thread t: c4 = t&31 (float4 channel, channels 4*c4..4*c4+3, head c4>>3)
//             part = t>>5 (8 partitions of the m axis, 25 m each)
// Phase A: logits S[h][m] = (Q . (K'+tK)) / sqrt(DH), NEG where masked.
// Phase B: per-wave softmax (wave w handles head w).
// Phase C: out = sum_m w[h][m] * (V'+tV), reduced across the 8 partitions.
// ---------------------------------------------------------------------------
__global__ __launch_bounds__(256) void attn_kernel(
    const float* __restrict__ Qo, const float* __restrict__ Kp,
    const float* __restrict__ Vp,
    const float* __restrict__ tK, const float* __restrict__ tV,
    const int* __restrict__ tmask, float* __restrict__ out)
{
    const int bl = blockIdx.x;          // 0..1599
    const int b  = bl / L;
    const int l  = bl % L;
    const int t  = threadIdx.x;
    const int c4   = t & 31;            // float4 channel index
    const int part = t >> 5;            // 0..7
    const int h    = c4 >> 3;           // head for this channel group

    __shared__ float  S[NH * L];        // logits, then softmax weights
    __shared__ float4 P[32 * 8];        // phase-C partials

    const bool rowmasked = (tmask[bl] != 0);
    const float4 q = ((const float4*)Qo)[bl * 32 + c4];

    const float4* Kp4 = (const float4*)Kp + (size_t)b * L * 32;
    const float4* tK4 = (const float4*)tK + (size_t)bl * L * 32;

    // ---- Phase A: logits ----
    for (int i = 0; i < 25; ++i) {
        const int m = part * 25 + i;
        const float4 kk = Kp4[m * 32 + c4];
        const float4 tt = tK4[m * 32 + c4];
        float v = fmaf(q.x, kk.x + tt.x,
                  fmaf(q.y, kk.y + tt.y,
                  fmaf(q.z, kk.z + tt.z,
                       q.w * (kk.w + tt.w))));
        v += __shfl_down(v, 4, 8);
        v += __shfl_down(v, 2, 8);
        v += __shfl_down(v, 1, 8);
        if ((t & 7) == 0) {
            const bool masked = rowmasked || (m > l);
            S[h * L + m] = masked ? NEGV : v * 0.17677669529663687f; // 1/sqrt(32)
        }
    }
    __syncthreads();

    // ---- Phase B: softmax, one wave per head ----
    {
        const int hw   = t >> 6;        // wave index = head
        const int lane = t & 63;
        float mx = -INFINITY;
        for (int m = lane; m < L; m += 64) mx = fmaxf(mx, S[hw * L + m]);
        #pragma unroll
        for (int off = 32; off; off >>= 1) mx = fmaxf(mx, __shfl_xor(mx, off));
        float s = 0.0f;
        for (int m = lane; m < L; m += 64) s += __expf(S[hw * L + m] - mx);
        #pragma unroll
        for (int off = 32; off; off >>= 1) s += __shfl_xor(s, off);
        const float inv = 1.0f / s;
        for (int m = lane; m < L; m += 64)
            S[hw * L + m] = __expf(S[hw * L + m] - mx) * inv;
    }
    __syncthreads();

    // ---- Phase C: weighted sum of (V' + tV) ----
    const float4* Vp4 = (const float4*)Vp + (size_t)b * L * 32;
    const float4* tV4 = (const float4*)tV + (size_t)bl * L * 32;
    float4 acc = make_float4(0.f, 0.f, 0.f, 0.f);
    for (int i = 0; i < 25; ++i) {
        const int m = part * 25 + i;
        const float w = S[h * L + m];
        const float4 vv = Vp4[m * 32 + c4];
        const float4 tt = tV4[m * 32 + c4];
        acc.x = fmaf(w, vv.x + tt.x, acc.x);
        acc.y = fmaf(w, vv.y + tt.y, acc.y);
        acc.z = fmaf(w, vv.z + tt.z, acc.z);
        acc.w = fmaf(w, vv.w + tt.w, acc.w);
    }
    P[c4 * 8 + part] = acc;
    __syncthreads();

    if (t < 32) {
        float4 tot = make_float4(0.f, 0.f, 0.f, 0.f);
        #pragma unroll
        for (int p = 0; p < 8; ++p) {
            const float4 a = P[t * 8 + p];
            tot.x += a.x; tot.y += a.y; tot.z += a.z; tot.w += a.w;
        }
        ((float4*)out)[bl * 32 + t] = tot;
    }
}

extern "C" void kernel_launch(void* const* d_in, const int* in_sizes, int n_in,
                              void* d_out, int out_size, void* d_ws, size_t ws_size,
                              hipStream_t stream) {
    const float* queries = (const float*)d_in[0];
    const float* keys    = (const float*)d_in[1];
    const int*   tmask   = (const int*)d_in[2];
    // d_in[3] = attn_mask: deterministic causal (m > l), recomputed in-kernel.
    const float* tK   = (const float*)d_in[4];
    const float* tV   = (const float*)d_in[5];
    const float* apK  = (const float*)d_in[6];
    const float* apV  = (const float*)d_in[7];
    const float* Qw   = (const float*)d_in[8];
    const float* Qb   = (const float*)d_in[9];
    const float* Kw   = (const float*)d_in[10];
    const float* Kb   = (const float*)d_in[11];
    const float* Vw   = (const float*)d_in[12];
    const float* Vb   = (const float*)d_in[13];
    float* out = (float*)d_out;

    // workspace: Q (819.2KB) | K' (819.2KB) | V' (819.2KB)
    float* Qo  = (float*)d_ws;
    float* Kpo = Qo  + (size_t)B * L * H;
    float* Vpo = Kpo + (size_t)B * L * H;

    proj_kernel<<<(B * L) / 8, 128, 0, stream>>>(
        queries, keys, apK, apV, Qw, Qb, Kw, Kb, Vw, Vb, Qo, Kpo, Vpo);

    attn_kernel<<<B * L, 256, 0, stream>>>(Qo, Kpo, Vpo, tK, tV, tmask, out);
}

// Round 2
// 377.858 us; speedup vs baseline: 1.0308x; 1.0308x over previous
//
#include <hip/hip_runtime.h>
#include <math.h>

#define B 8
#define L 200
#define H 128
#define NH 4
#define DH 32
#define NEGV (-4294967295.0f)   /* -2^32 + 1 */

// ---------------------------------------------------------------------------
// Kernel 1: fused projections.
//   Qo  = queries @ Qw.T + Qb
//   Kpo = keys    @ Kw.T + Kb + abs_pos_K
//   Vpo = keys    @ Vw.T + Vb + abs_pos_V
// One block per 8 rows (1600 rows -> 200 blocks), 128 threads = one output
// channel each. Weights (3 x 64KB) stay hot in L2 across blocks.
// ---------------------------------------------------------------------------
__global__ __launch_bounds__(128) void proj_kernel(
    const float* __restrict__ queries, const float* __restrict__ keys,
    const float* __restrict__ apK, const float* __restrict__ apV,
    const float* __restrict__ Qw, const float* __restrict__ Qb,
    const float* __restrict__ Kw, const float* __restrict__ Kb,
    const float* __restrict__ Vw, const float* __restrict__ Vb,
    float* __restrict__ Qo, float* __restrict__ Kpo, float* __restrict__ Vpo)
{
    const int j    = threadIdx.x;        // output channel 0..127
    const int row0 = blockIdx.x * 8;     // first of 8 rows

    __shared__ float4 qrow[8 * 32];
    __shared__ float4 krow[8 * 32];

    const float4* q4 = (const float4*)queries + row0 * 32;
    const float4* k4 = (const float4*)keys    + row0 * 32;
    for (int idx = j; idx < 256; idx += 128) { qrow[idx] = q4[idx]; krow[idx] = k4[idx]; }
    __syncthreads();

    float accQ[8], accK[8], accV[8];
    const float qb = Qb[j], kb = Kb[j], vb = Vb[j];
    #pragma unroll
    for (int r = 0; r < 8; ++r) { accQ[r] = qb; accK[r] = kb; accV[r] = vb; }

    const float4* Qw4 = (const float4*)Qw + j * 32;
    const float4* Kw4 = (const float4*)Kw + j * 32;
    const float4* Vw4 = (const float4*)Vw + j * 32;

    for (int k = 0; k < 32; ++k) {
        const float4 wq = Qw4[k];
        const float4 wk = Kw4[k];
        const float4 wv = Vw4[k];
        #pragma unroll
        for (int r = 0; r < 8; ++r) {
            const float4 x = qrow[r * 32 + k];
            accQ[r] = fmaf(wq.x, x.x, fmaf(wq.y, x.y, fmaf(wq.z, x.z, fmaf(wq.w, x.w, accQ[r]))));
            const float4 y = krow[r * 32 + k];
            accK[r] = fmaf(wk.x, y.x, fmaf(wk.y, y.y, fmaf(wk.z, y.z, fmaf(wk.w, y.w, accK[r]))));
            accV[r] = fmaf(wv.x, y.x, fmaf(wv.y, y.y, fmaf(wv.z, y.z, fmaf(wv.w, y.w, accV[r]))));
        }
    }

    #pragma unroll
    for (int r = 0; r < 8; ++r) {
        const int i = row0 + r;
        Qo [i * H + j] = accQ[r];
        Kpo[i * H + j] = accK[r] + apK[i * H + j];
        Vpo[i * H + j] = accV[r] + apV[i * H + j];
    }
}

// ---------------------------------------------------------------------------
// Kernel 2: attention. One block per (b,l); 512 threads (8 waves).
//   thread t: c4 = t&31 (float4 channel, head c4>>3), part = t>>5 (0..15)
//   m-mapping: m = part + 16*i  -> per step the block touches rows
//   [16i,16i+16) = 8KB CONTIGUOUS; each wave-load covers 1KB contiguous.
//   Loads batched 8-deep per thread (4 m-steps x {K',tK}) for MLP.
// ---------------------------------------------------------------------------
__global__ __launch_bounds__(512) void attn_kernel(
    const float* __restrict__ Qo, const float* __restrict__ Kp,
    const float* __restrict__ Vp,
    const float* __restrict__ tK, const float* __restrict__ tV,
    const int* __restrict__ tmask, float* __restrict__ out)
{
    const int bl = blockIdx.x;          // 0..1599
    const int b  = bl / L;
    const int l  = bl % L;
    const int t  = threadIdx.x;
    const int c4   = t & 31;            // float4 channel index
    const int part = t >> 5;            // 0..15
    const int h    = c4 >> 3;           // head for this channel group

    __shared__ float  S[NH * L];        // logits, then softmax weights
    __shared__ float4 P[32 * 17];       // phase-C partials (stride 17: no 32-way conflict)

    const bool rowmasked = (tmask[bl] != 0);
    const float4 q = ((const float4*)Qo)[bl * 32 + c4];

    const float4* Kp4 = (const float4*)Kp + (size_t)b * L * 32;
    const float4* tK4 = (const float4*)tK + (size_t)bl * L * 32;

    // ---- Phase A: logits. 200 = 16*12 + 8 ----
    #pragma unroll
    for (int i = 0; i < 3; ++i) {
        float4 kk[4], tt[4];
        #pragma unroll
        for (int u = 0; u < 4; ++u) {
            const int m = part + 16 * (4 * i + u);
            kk[u] = Kp4[m * 32 + c4];
            tt[u] = tK4[m * 32 + c4];
        }
        #pragma unroll
        for (int u = 0; u < 4; ++u) {
            const int m = part + 16 * (4 * i + u);
            float v = fmaf(q.x, kk[u].x + tt[u].x,
                      fmaf(q.y, kk[u].y + tt[u].y,
                      fmaf(q.z, kk[u].z + tt[u].z,
                           q.w * (kk[u].w + tt[u].w))));
            v += __shfl_down(v, 4, 8);
            v += __shfl_down(v, 2, 8);
            v += __shfl_down(v, 1, 8);
            if ((t & 7) == 0) {
                const bool masked = rowmasked || (m > l);
                S[h * L + m] = masked ? NEGV : v * 0.17677669529663687f; // 1/sqrt(32)
            }
        }
    }
    if (part < 8) {                      // tail rows 192..199
        const int m = part + 192;
        const float4 kk = Kp4[m * 32 + c4];
        const float4 tt = tK4[m * 32 + c4];
        float v = fmaf(q.x, kk.x + tt.x,
                  fmaf(q.y, kk.y + tt.y,
                  fmaf(q.z, kk.z + tt.z,
                       q.w * (kk.w + tt.w))));
        v += __shfl_down(v, 4, 8);
        v += __shfl_down(v, 2, 8);
        v += __shfl_down(v, 1, 8);
        if ((t & 7) == 0) {
            const bool masked = rowmasked || (m > l);
            S[h * L + m] = masked ? NEGV : v * 0.17677669529663687f;
        }
    }
    __syncthreads();

    // ---- Phase B: softmax, waves 0..3 handle heads 0..3 ----
    if (t < 256) {
        const int hw   = t >> 6;        // wave index = head
        const int lane = t & 63;
        float mx = -INFINITY;
        for (int m = lane; m < L; m += 64) mx = fmaxf(mx, S[hw * L + m]);
        #pragma unroll
        for (int off = 32; off; off >>= 1) mx = fmaxf(mx, __shfl_xor(mx, off));
        float s = 0.0f;
        for (int m = lane; m < L; m += 64) s += __expf(S[hw * L + m] - mx);
        #pragma unroll
        for (int off = 32; off; off >>= 1) s += __shfl_xor(s, off);
        const float inv = 1.0f / s;
        for (int m = lane; m < L; m += 64)
            S[hw * L + m] = __expf(S[hw * L + m] - mx) * inv;
    }
    __syncthreads();

    // ---- Phase C: weighted sum of (V' + tV) ----
    const float4* Vp4 = (const float4*)Vp + (size_t)b * L * 32;
    const float4* tV4 = (const float4*)tV + (size_t)bl * L * 32;
    float4 acc = make_float4(0.f, 0.f, 0.f, 0.f);
    #pragma unroll
    for (int i = 0; i < 3; ++i) {
        float4 vv[4], tt[4];
        #pragma unroll
        for (int u = 0; u < 4; ++u) {
            const int m = part + 16 * (4 * i + u);
            vv[u] = Vp4[m * 32 + c4];
            tt[u] = tV4[m * 32 + c4];
        }
        #pragma unroll
        for (int u = 0; u < 4; ++u) {
            const int m = part + 16 * (4 * i + u);
            const float w = S[h * L + m];
            acc.x = fmaf(w, vv[u].x + tt[u].x, acc.x);
            acc.y = fmaf(w, vv[u].y + tt[u].y, acc.y);
            acc.z = fmaf(w, vv[u].z + tt[u].z, acc.z);
            acc.w = fmaf(w, vv[u].w + tt[u].w, acc.w);
        }
    }
    if (part < 8) {
        const int m = part + 192;
        const float w = S[h * L + m];
        const float4 vv = Vp4[m * 32 + c4];
        const float4 tt = tV4[m * 32 + c4];
        acc.x = fmaf(w, vv.x + tt.x, acc.x);
        acc.y = fmaf(w, vv.y + tt.y, acc.y);
        acc.z = fmaf(w, vv.z + tt.z, acc.z);
        acc.w = fmaf(w, vv.w + tt.w, acc.w);
    }
    P[c4 * 17 + part] = acc;
    __syncthreads();

    if (t < 32) {
        float4 tot = make_float4(0.f, 0.f, 0.f, 0.f);
        #pragma unroll
        for (int p = 0; p < 16; ++p) {
            const float4 a = P[t * 17 + p];
            tot.x += a.x; tot.y += a.y; tot.z += a.z; tot.w += a.w;
        }
        ((float4*)out)[bl * 32 + t] = tot;
    }
}

extern "C" void kernel_launch(void* const* d_in, const int* in_sizes, int n_in,
                              void* d_out, int out_size, void* d_ws, size_t ws_size,
                              hipStream_t stream) {
    const float* queries = (const float*)d_in[0];
    const float* keys    = (const float*)d_in[1];
    const int*   tmask   = (const int*)d_in[2];
    // d_in[3] = attn_mask: deterministic causal (m > l), recomputed in-kernel.
    const float* tK   = (const float*)d_in[4];
    const float* tV   = (const float*)d_in[5];
    const float* apK  = (const float*)d_in[6];
    const float* apV  = (const float*)d_in[7];
    const float* Qw   = (const float*)d_in[8];
    const float* Qb   = (const float*)d_in[9];
    const float* Kw   = (const float*)d_in[10];
    const float* Kb   = (const float*)d_in[11];
    const float* Vw   = (const float*)d_in[12];
    const float* Vb   = (const float*)d_in[13];
    float* out = (float*)d_out;

    // workspace: Q (819.2KB) | K' (819.2KB) | V' (819.2KB)
    float* Qo  = (float*)d_ws;
    float* Kpo = Qo  + (size_t)B * L * H;
    float* Vpo = Kpo + (size_t)B * L * H;

    proj_kernel<<<(B * L) / 8, 128, 0, stream>>>(
        queries, keys, apK, apV, Qw, Qb, Kw, Kb, Vw, Vb, Qo, Kpo, Vpo);

    attn_kernel<<<B * L, 512, 0, stream>>>(Qo, Kpo, Vpo, tK, tV, tmask, out);
}

// Round 3
// 344.205 us; speedup vs baseline: 1.1316x; 1.0978x over previous
//
#include <hip/hip_runtime.h>
#include <math.h>

#define B 8
#define L 200
#define H 128
#define NH 4
#define DH 32
#define NEGV (-4294967295.0f)   /* -2^32 + 1 */

// ---------------------------------------------------------------------------
// Kernel 1: fused projections.
//   Qo  = queries @ Qw.T + Qb
//   Kpo = keys    @ Kw.T + Kb + abs_pos_K
//   Vpo = keys    @ Vw.T + Vb + abs_pos_V
// ---------------------------------------------------------------------------
__global__ __launch_bounds__(128) void proj_kernel(
    const float* __restrict__ queries, const float* __restrict__ keys,
    const float* __restrict__ apK, const float* __restrict__ apV,
    const float* __restrict__ Qw, const float* __restrict__ Qb,
    const float* __restrict__ Kw, const float* __restrict__ Kb,
    const float* __restrict__ Vw, const float* __restrict__ Vb,
    float* __restrict__ Qo, float* __restrict__ Kpo, float* __restrict__ Vpo)
{
    const int j    = threadIdx.x;        // output channel 0..127
    const int row0 = blockIdx.x * 8;     // first of 8 rows

    __shared__ float4 qrow[8 * 32];
    __shared__ float4 krow[8 * 32];

    const float4* q4 = (const float4*)queries + row0 * 32;
    const float4* k4 = (const float4*)keys    + row0 * 32;
    for (int idx = j; idx < 256; idx += 128) { qrow[idx] = q4[idx]; krow[idx] = k4[idx]; }
    __syncthreads();

    float accQ[8], accK[8], accV[8];
    const float qb = Qb[j], kb = Kb[j], vb = Vb[j];
    #pragma unroll
    for (int r = 0; r < 8; ++r) { accQ[r] = qb; accK[r] = kb; accV[r] = vb; }

    const float4* Qw4 = (const float4*)Qw + j * 32;
    const float4* Kw4 = (const float4*)Kw + j * 32;
    const float4* Vw4 = (const float4*)Vw + j * 32;

    for (int k = 0; k < 32; ++k) {
        const float4 wq = Qw4[k];
        const float4 wk = Kw4[k];
        const float4 wv = Vw4[k];
        #pragma unroll
        for (int r = 0; r < 8; ++r) {
            const float4 x = qrow[r * 32 + k];
            accQ[r] = fmaf(wq.x, x.x, fmaf(wq.y, x.y, fmaf(wq.z, x.z, fmaf(wq.w, x.w, accQ[r]))));
            const float4 y = krow[r * 32 + k];
            accK[r] = fmaf(wk.x, y.x, fmaf(wk.y, y.y, fmaf(wk.z, y.z, fmaf(wk.w, y.w, accK[r]))));
            accV[r] = fmaf(wv.x, y.x, fmaf(wv.y, y.y, fmaf(wv.z, y.z, fmaf(wv.w, y.w, accV[r]))));
        }
    }

    #pragma unroll
    for (int r = 0; r < 8; ++r) {
        const int i = row0 + r;
        Qo [i * H + j] = accQ[r];
        Kpo[i * H + j] = accK[r] + apK[i * H + j];
        Vpo[i * H + j] = accV[r] + apV[i * H + j];
    }
}

// ---------------------------------------------------------------------------
// Kernel 2: attention. One block per (b,l); 512 threads (8 waves).
//   thread t: c4 = t&31 (float4 channel, head c4>>3), part = t>>5 (0..15)
//   m-mapping: m = part + 16*i  (contiguous 8KB per step across the block).
// CAUSAL SKIP: only m <= l rows are loaded (masked logits are NEG and masked
// weights are exactly 0). Fully time-masked rows skip phases A/B entirely:
// softmax of all-NEG is exactly uniform 1/200, but needs all 200 V rows.
// Grid is ordered heavy-blocks-first (l = 199 - bl/8) for load balance.
// ---------------------------------------------------------------------------
__global__ __launch_bounds__(512) void attn_kernel(
    const float* __restrict__ Qo, const float* __restrict__ Kp,
    const float* __restrict__ Vp,
    const float* __restrict__ tK, const float* __restrict__ tV,
    const int* __restrict__ tmask, float* __restrict__ out)
{
    const int bid = blockIdx.x;         // 0..1599
    const int b   = bid & 7;
    const int l   = 199 - (bid >> 3);   // heavy rows dispatched first
    const int bl  = b * L + l;
    const int t  = threadIdx.x;
    const int c4   = t & 31;            // float4 channel index
    const int part = t >> 5;            // 0..15
    const int h    = c4 >> 3;           // head for this channel group

    __shared__ float  S[NH * L];        // logits, then softmax weights
    __shared__ float4 P[32 * 17];       // phase-C partials (stride 17)

    const bool rowmasked = (tmask[bl] != 0);
    const float4 q = ((const float4*)Qo)[bl * 32 + c4];

    const float4* Kp4 = (const float4*)Kp + (size_t)b * L * 32;
    const float4* tK4 = (const float4*)tK + (size_t)bl * L * 32;

    // ---- Phase A: logits for m in [0, l] (skipped if row fully masked) ----
    if (!rowmasked) {
        const int nsteps = (l + 16) >> 4;     // ceil((l+1)/16)
        for (int i0 = 0; i0 < nsteps; i0 += 4) {
            float4 kk[4], tt[4];
            int mm[4];
            #pragma unroll
            for (int u = 0; u < 4; ++u) {
                const int m = part + 16 * (i0 + u);
                mm[u] = m;
                if (m <= l) {
                    kk[u] = Kp4[m * 32 + c4];
                    tt[u] = tK4[m * 32 + c4];
                }
            }
            #pragma unroll
            for (int u = 0; u < 4; ++u) {
                const int m = mm[u];
                float v = 0.0f;
                if (m <= l) {
                    v = fmaf(q.x, kk[u].x + tt[u].x,
                        fmaf(q.y, kk[u].y + tt[u].y,
                        fmaf(q.z, kk[u].z + tt[u].z,
                             q.w * (kk[u].w + tt[u].w))));
                }
                v += __shfl_down(v, 4, 8);
                v += __shfl_down(v, 2, 8);
                v += __shfl_down(v, 1, 8);
                if ((t & 7) == 0 && m <= l)
                    S[h * L + m] = v * 0.17677669529663687f;  // 1/sqrt(32)
            }
        }
    }
    __syncthreads();

    // ---- Phase B: softmax over m in [0, l], waves 0..3 = heads 0..3 ----
    if (!rowmasked && t < 256) {
        const int hw   = t >> 6;        // wave index = head
        const int lane = t & 63;
        float mx = -INFINITY;
        for (int m = lane; m <= l; m += 64) mx = fmaxf(mx, S[hw * L + m]);
        #pragma unroll
        for (int off = 32; off; off >>= 1) mx = fmaxf(mx, __shfl_xor(mx, off));
        float s = 0.0f;
        for (int m = lane; m <= l; m += 64) s += __expf(S[hw * L + m] - mx);
        #pragma unroll
        for (int off = 32; off; off >>= 1) s += __shfl_xor(s, off);
        const float inv = 1.0f / s;
        for (int m = lane; m <= l; m += 64)
            S[hw * L + m] = __expf(S[hw * L + m] - mx) * inv;
    }
    __syncthreads();

    // ---- Phase C: out = sum_m w * (V' + tV) ----
    // masked row: w = 1/200 for all 200 m; else w = S[h][m] for m <= l.
    const float4* Vp4 = (const float4*)Vp + (size_t)b * L * 32;
    const float4* tV4 = (const float4*)tV + (size_t)bl * L * 32;
    const int   nmV = rowmasked ? L : (l + 1);
    const float wU  = 1.0f / (float)L;
    float4 acc = make_float4(0.f, 0.f, 0.f, 0.f);
    const int nstepsV = (nmV + 15) >> 4;
    for (int i0 = 0; i0 < nstepsV; i0 += 4) {
        float4 vv[4], tt[4];
        int mm[4];
        #pragma unroll
        for (int u = 0; u < 4; ++u) {
            const int m = part + 16 * (i0 + u);
            mm[u] = m;
            if (m < nmV) {
                vv[u] = Vp4[m * 32 + c4];
                tt[u] = tV4[m * 32 + c4];
            }
        }
        #pragma unroll
        for (int u = 0; u < 4; ++u) {
            const int m = mm[u];
            if (m < nmV) {
                const float w = rowmasked ? wU : S[h * L + m];
                acc.x = fmaf(w, vv[u].x + tt[u].x, acc.x);
                acc.y = fmaf(w, vv[u].y + tt[u].y, acc.y);
                acc.z = fmaf(w, vv[u].z + tt[u].z, acc.z);
                acc.w = fmaf(w, vv[u].w + tt[u].w, acc.w);
            }
        }
    }
    P[c4 * 17 + part] = acc;
    __syncthreads();

    if (t < 32) {
        float4 tot = make_float4(0.f, 0.f, 0.f, 0.f);
        #pragma unroll
        for (int p = 0; p < 16; ++p) {
            const float4 a = P[t * 17 + p];
            tot.x += a.x; tot.y += a.y; tot.z += a.z; tot.w += a.w;
        }
        ((float4*)out)[bl * 32 + t] = tot;
    }
}

extern "C" void kernel_launch(void* const* d_in, const int* in_sizes, int n_in,
                              void* d_out, int out_size, void* d_ws, size_t ws_size,
                              hipStream_t stream) {
    const float* queries = (const float*)d_in[0];
    const float* keys    = (const float*)d_in[1];
    const int*   tmask   = (const int*)d_in[2];
    // d_in[3] = attn_mask: deterministic causal (m > l), recomputed in-kernel.
    const float* tK   = (const float*)d_in[4];
    const float* tV   = (const float*)d_in[5];
    const float* apK  = (const float*)d_in[6];
    const float* apV  = (const float*)d_in[7];
    const float* Qw   = (const float*)d_in[8];
    const float* Qb   = (const float*)d_in[9];
    const float* Kw   = (const float*)d_in[10];
    const float* Kb   = (const float*)d_in[11];
    const float* Vw   = (const float*)d_in[12];
    const float* Vb   = (const float*)d_in[13];
    float* out = (float*)d_out;

    // workspace: Q (819.2KB) | K' (819.2KB) | V' (819.2KB)
    float* Qo  = (float*)d_ws;
    float* Kpo = Qo  + (size_t)B * L * H;
    float* Vpo = Kpo + (size_t)B * L * H;

    proj_kernel<<<(B * L) / 8, 128, 0, stream>>>(
        queries, keys, apK, apV, Qw, Qb, Kw, Kb, Vw, Vb, Qo, Kpo, Vpo);

    attn_kernel<<<B * L, 512, 0, stream>>>(Qo, Kpo, Vpo, tK, tV, tmask, out);
}